// Round 1
// baseline (949.114 us; speedup 1.0000x reference)
//
#include <hip/hip_runtime.h>

#define NTOK 32768
#define CDIM 256
#define KCODE 1024
#define C4 64   // CDIM/4

// ---------------- K1: normalize codebook, compute en2 = sum(en^2) -----------
__global__ void k_norm_emb(const float* __restrict__ emb,
                           float* __restrict__ en, float* __restrict__ en2) {
    int k = blockIdx.x;
    int l = threadIdx.x;               // 64 lanes, 4 floats each
    float4 v = reinterpret_cast<const float4*>(emb)[k * C4 + l];
    float ss = v.x*v.x + v.y*v.y + v.z*v.z + v.w*v.w;
    #pragma unroll
    for (int o = 32; o >= 1; o >>= 1) ss += __shfl_xor(ss, o, 64);
    float den = fmaxf(sqrtf(ss), 1e-12f);
    float4 e;
    e.x = v.x / den; e.y = v.y / den; e.z = v.z / den; e.w = v.w / den;
    reinterpret_cast<float4*>(en)[k * C4 + l] = e;
    float s2 = e.x*e.x + e.y*e.y + e.z*e.z + e.w*e.w;
    #pragma unroll
    for (int o = 32; o >= 1; o >>= 1) s2 += __shfl_xor(s2, o, 64);
    if (l == 0) en2[k] = s2;
}

// ---------------- K2: transpose+normalize z (NCHW -> (T,C) row-major) -------
// 32 tokens per block. LDS tile [c][tok] with rotation swizzle (tok+c)&31.
__global__ void k_norm_z(const float* __restrict__ z,
                         float* __restrict__ znt, float* __restrict__ znt2) {
    __shared__ float zsb[CDIM * 32];   // 32 KB, [c][ (tok+c)&31 ]
    __shared__ float ssp[256];
    __shared__ float dens[32];
    int tid = threadIdx.x;
    int t0  = blockIdx.x * 32;
    int n   = t0 >> 10;
    int thw0 = t0 & 1023;

    // phase 1: coalesced read (lanes = tokens), per-thread c-stripe of 32
    int l = tid & 31, grp = tid >> 5;          // 8 c-stripes
    const float* zb = z + (((size_t)(n * CDIM)) << 10) + thw0 + l;
    float ss = 0.f;
    int c0 = grp * 32;
    for (int cc = 0; cc < 32; ++cc) {
        int c = c0 + cc;
        float v = zb[((size_t)c) << 10];
        zsb[c * 32 + ((l + c) & 31)] = v;
        ss += v * v;
    }
    ssp[tid] = ss;
    __syncthreads();
    if (tid < 32) {
        float tot = 0.f;
        #pragma unroll
        for (int g = 0; g < 8; ++g) tot += ssp[g * 32 + tid];
        dens[tid] = fmaxf(sqrtf(tot), 1e-12f);
    }
    __syncthreads();

    // phase 2: coalesced write (lanes = channels), also compute zn2 per token
    int l2 = tid & 63, tg = tid >> 6;          // 4 token-groups of 8
    for (int it = 0; it < 8; ++it) {
        int tok = tg * 8 + it;
        float den = dens[tok];
        float s2 = 0.f;
        #pragma unroll
        for (int cq = 0; cq < 4; ++cq) {
            int c = cq * 64 + l2;
            float v = zsb[c * 32 + ((tok + c) & 31)] / den;
            znt[((size_t)(t0 + tok)) * CDIM + c] = v;
            s2 += v * v;
        }
        #pragma unroll
        for (int o = 32; o >= 1; o >>= 1) s2 += __shfl_xor(s2, o, 64);
        if (l2 == 0) znt2[t0 + tok] = s2;
    }
}

// ---------------- K3: fused fp32 GEMM + argmin ------------------------------
// 64 tokens/block, 256 threads (ty 0..15, tx 0..15), TM=4 TN=4.
// zn tile in 64KB swizzled LDS; codebook streamed from L2.
__global__ __launch_bounds__(256, 2) void k_argmin(
        const float* __restrict__ znt, const float* __restrict__ znt2,
        const float* __restrict__ en,  const float* __restrict__ en2,
        int* __restrict__ idxb, float* __restrict__ idxf) {
    __shared__ float4 zs4[64 * 64];    // exactly 64 KB, [m][ c4 ^ (m&15) ]
    int tid = threadIdx.x;
    int t0  = blockIdx.x * 64;

    const float4* zg = reinterpret_cast<const float4*>(znt) + (size_t)t0 * C4;
    #pragma unroll
    for (int it = 0; it < 16; ++it) {
        int f4 = it * 256 + tid;
        int m = f4 >> 6, c4 = f4 & 63;
        zs4[m * 64 + (c4 ^ (m & 15))] = zg[f4];
    }
    __syncthreads();

    int tx = tid & 15, ty = tid >> 4;
    float z2[4];
    #pragma unroll
    for (int i = 0; i < 4; ++i) z2[i] = znt2[t0 + ty + 16 * i];

    float bestV[4]; int bestI[4];
    #pragma unroll
    for (int i = 0; i < 4; ++i) { bestV[i] = 3.4e38f; bestI[i] = 0; }

    const float4* eg = reinterpret_cast<const float4*>(en);

    for (int ch = 0; ch < 16; ++ch) {
        int kb = ch * 64 + tx;
        float e2[4];
        #pragma unroll
        for (int j = 0; j < 4; ++j) e2[j] = en2[kb + 16 * j];

        float4 acc[4][4];
        #pragma unroll
        for (int i = 0; i < 4; ++i)
            #pragma unroll
            for (int j = 0; j < 4; ++j) acc[i][j] = make_float4(0.f, 0.f, 0.f, 0.f);

        #pragma unroll 8
        for (int c4 = 0; c4 < 64; ++c4) {
            float4 za[4], eb[4];
            #pragma unroll
            for (int i = 0; i < 4; ++i)
                za[i] = zs4[(ty + 16 * i) * 64 + (c4 ^ ty)];   // (ty+16i)&15 == ty
            #pragma unroll
            for (int j = 0; j < 4; ++j)
                eb[j] = eg[(size_t)(kb + 16 * j) * C4 + c4];
            #pragma unroll
            for (int i = 0; i < 4; ++i)
                #pragma unroll
                for (int j = 0; j < 4; ++j) {
                    acc[i][j].x += za[i].x * eb[j].x;
                    acc[i][j].y += za[i].y * eb[j].y;
                    acc[i][j].z += za[i].z * eb[j].z;
                    acc[i][j].w += za[i].w * eb[j].w;
                }
        }

        #pragma unroll
        for (int i = 0; i < 4; ++i)
            #pragma unroll
            for (int j = 0; j < 4; ++j) {
                float dp = (acc[i][j].x + acc[i][j].y) + (acc[i][j].z + acc[i][j].w);
                // replicate reference rounding: fl(fl(zn2+en2) - fl(2*dot))
                float s  = z2[i] + e2[j];
                float val = s - 2.0f * dp;
                int kk = kb + 16 * j;
                if (val < bestV[i]) { bestV[i] = val; bestI[i] = kk; }
            }
    }

    // reduce across the 16 tx lanes (same ty group); tie -> smaller index
    #pragma unroll
    for (int i = 0; i < 4; ++i) {
        #pragma unroll
        for (int off = 1; off < 16; off <<= 1) {
            float vo = __shfl_xor(bestV[i], off, 16);
            int   io = __shfl_xor(bestI[i], off, 16);
            if (vo < bestV[i] || (vo == bestV[i] && io < bestI[i])) {
                bestV[i] = vo; bestI[i] = io;
            }
        }
        if (tx == 0) {
            int t = t0 + ty + 16 * i;
            idxb[t] = bestI[i];
            idxf[t] = (float)bestI[i];
        }
    }
}

// ---------------- K4: gather epilogue (quant = emb[idx], NCHW) --------------
__global__ void k_gather(const float* __restrict__ emb,
                         const int* __restrict__ idxb, float* __restrict__ out) {
    int o  = blockIdx.x * 256 + threadIdx.x;
    int hw = o & 1023;
    int nc = o >> 10;
    int c  = nc & 255;
    int n  = nc >> 8;
    int t  = (n << 10) | hw;
    int k  = idxb[t];
    out[o] = emb[(size_t)k * CDIM + c];
}

extern "C" void kernel_launch(void* const* d_in, const int* in_sizes, int n_in,
                              void* d_out, int out_size, void* d_ws, size_t ws_size,
                              hipStream_t stream) {
    const float* z   = (const float*)d_in[0];
    const float* emb = (const float*)d_in[1];
    float* out  = (float*)d_out;
    float* znt  = out;                         // quant region doubles as zn scratch
    float* idxf = out + (size_t)NTOK * CDIM;   // index output (float) tail

    float* en   = (float*)d_ws;                // 1 MB
    float* en2  = en + (size_t)KCODE * CDIM;   // 4 KB
    float* znt2 = en2 + KCODE;                 // 128 KB
    int*   idxb = (int*)(znt2 + NTOK);         // 128 KB

    k_norm_emb<<<KCODE, 64, 0, stream>>>(emb, en, en2);
    k_norm_z<<<NTOK / 32, 256, 0, stream>>>(z, znt, znt2);
    k_argmin<<<NTOK / 64, 256, 0, stream>>>(znt, znt2, en, en2, idxb, idxf);
    k_gather<<<(NTOK * CDIM) / 256, 256, 0, stream>>>(emb, idxb, out);
}

// Round 2
// 370.097 us; speedup vs baseline: 2.5645x; 2.5645x over previous
//
#include <hip/hip_runtime.h>

#define NTOK 32768
#define CDIM 256
#define KCODE 1024
#define C4 64   // CDIM/4

// ---------------- K1: normalize codebook, compute en2 = sum(en^2) -----------
__global__ void k_norm_emb(const float* __restrict__ emb,
                           float* __restrict__ en, float* __restrict__ en2) {
    int k = blockIdx.x;
    int l = threadIdx.x;               // 64 lanes, 4 floats each
    float4 v = reinterpret_cast<const float4*>(emb)[k * C4 + l];
    float ss = v.x*v.x + v.y*v.y + v.z*v.z + v.w*v.w;
    #pragma unroll
    for (int o = 32; o >= 1; o >>= 1) ss += __shfl_xor(ss, o, 64);
    float den = fmaxf(sqrtf(ss), 1e-12f);
    float4 e;
    e.x = v.x / den; e.y = v.y / den; e.z = v.z / den; e.w = v.w / den;
    reinterpret_cast<float4*>(en)[k * C4 + l] = e;
    float s2 = e.x*e.x + e.y*e.y + e.z*e.z + e.w*e.w;
    #pragma unroll
    for (int o = 32; o >= 1; o >>= 1) s2 += __shfl_xor(s2, o, 64);
    if (l == 0) en2[k] = s2;
}

// ---------------- K2: transpose+normalize z (NCHW -> (T,C) row-major) -------
__global__ void k_norm_z(const float* __restrict__ z,
                         float* __restrict__ znt, float* __restrict__ znt2) {
    __shared__ float zsb[CDIM * 32];   // 32 KB, [c][ (tok+c)&31 ]
    __shared__ float ssp[256];
    __shared__ float dens[32];
    int tid = threadIdx.x;
    int t0  = blockIdx.x * 32;
    int n   = t0 >> 10;
    int thw0 = t0 & 1023;

    int l = tid & 31, grp = tid >> 5;          // 8 c-stripes
    const float* zb = z + (((size_t)(n * CDIM)) << 10) + thw0 + l;
    float ss = 0.f;
    int c0 = grp * 32;
    for (int cc = 0; cc < 32; ++cc) {
        int c = c0 + cc;
        float v = zb[((size_t)c) << 10];
        zsb[c * 32 + ((l + c) & 31)] = v;
        ss += v * v;
    }
    ssp[tid] = ss;
    __syncthreads();
    if (tid < 32) {
        float tot = 0.f;
        #pragma unroll
        for (int g = 0; g < 8; ++g) tot += ssp[g * 32 + tid];
        dens[tid] = fmaxf(sqrtf(tot), 1e-12f);
    }
    __syncthreads();

    int l2 = tid & 63, tg = tid >> 6;          // 4 token-groups of 8
    for (int it = 0; it < 8; ++it) {
        int tok = tg * 8 + it;
        float den = dens[tok];
        float s2 = 0.f;
        #pragma unroll
        for (int cq = 0; cq < 4; ++cq) {
            int c = cq * 64 + l2;
            float v = zsb[c * 32 + ((tok + c) & 31)] / den;
            znt[((size_t)(t0 + tok)) * CDIM + c] = v;
            s2 += v * v;
        }
        #pragma unroll
        for (int o = 32; o >= 1; o >>= 1) s2 += __shfl_xor(s2, o, 64);
        if (l2 == 0) znt2[t0 + tok] = s2;
    }
}

// ---------------- K3: tiled fp32 GEMM + argmin (double-buffered LDS) --------
// 64 tokens/block. 16 chunks of 64 codes; BK=64 double-buffered.
// LDS layout: [buf][row][col4 ^ (row&15)] float4 — conflict-free on both
// staging writes and compute reads. 256 threads: tx=tid&15 (codes),
// ty=tid>>4 (tokens); TM=TN=4 register tile, float4 K-partials.
__global__ __launch_bounds__(256, 2) void k_argmin(
        const float* __restrict__ znt, const float* __restrict__ znt2,
        const float* __restrict__ en,  const float* __restrict__ en2,
        int* __restrict__ idxb, float* __restrict__ idxf) {
    __shared__ float4 zs[2][64][16];   // 32 KB
    __shared__ float4 es[2][64][16];   // 32 KB
    int tid = threadIdx.x;
    int t0  = blockIdx.x * 64;
    int tx = tid & 15, ty = tid >> 4;

    const float4* zg = reinterpret_cast<const float4*>(znt) + (size_t)t0 * C4;
    const float4* eg = reinterpret_cast<const float4*>(en);

    float z2[4];
    #pragma unroll
    for (int i = 0; i < 4; ++i) z2[i] = znt2[t0 + ty + 16 * i];

    float bestV[4]; int bestI[4];
    #pragma unroll
    for (int i = 0; i < 4; ++i) { bestV[i] = 3.4e38f; bestI[i] = 0; }

    int scol = tx ^ ty;                // swizzled store col, rows ty+16*it

    // prologue: stage (ch=0, ks=0) into buffer 0
    float4 zf[4], ef[4];
    #pragma unroll
    for (int it = 0; it < 4; ++it) {
        int r = ty + 16 * it;
        zf[it] = zg[(size_t)r * C4 + tx];
        ef[it] = eg[(size_t)r * C4 + tx];
    }
    #pragma unroll
    for (int it = 0; it < 4; ++it) {
        zs[0][ty + 16 * it][scol] = zf[it];
        es[0][ty + 16 * it][scol] = ef[it];
    }
    __syncthreads();

    int cur = 0;
    for (int ch = 0; ch < 16; ++ch) {
        float4 acc[4][4];
        #pragma unroll
        for (int i = 0; i < 4; ++i)
            #pragma unroll
            for (int j = 0; j < 4; ++j) acc[i][j] = make_float4(0.f, 0.f, 0.f, 0.f);

        for (int ks = 0; ks < 4; ++ks) {
            bool last = (ch == 15) && (ks == 3);
            if (!last) {
                int nks = (ks + 1) & 3;
                int nch = (ks == 3) ? ch + 1 : ch;
                #pragma unroll
                for (int it = 0; it < 4; ++it) {
                    int r = ty + 16 * it;
                    zf[it] = zg[(size_t)r * C4 + nks * 16 + tx];
                    ef[it] = eg[(size_t)(nch * 64 + r) * C4 + nks * 16 + tx];
                }
            }

            #pragma unroll 4
            for (int k4 = 0; k4 < 16; ++k4) {
                float4 za[4], eb[4];
                #pragma unroll
                for (int i = 0; i < 4; ++i) za[i] = zs[cur][ty + 16 * i][k4 ^ ty];
                #pragma unroll
                for (int j = 0; j < 4; ++j) eb[j] = es[cur][tx + 16 * j][k4 ^ tx];
                #pragma unroll
                for (int i = 0; i < 4; ++i)
                    #pragma unroll
                    for (int j = 0; j < 4; ++j) {
                        acc[i][j].x += za[i].x * eb[j].x;
                        acc[i][j].y += za[i].y * eb[j].y;
                        acc[i][j].z += za[i].z * eb[j].z;
                        acc[i][j].w += za[i].w * eb[j].w;
                    }
            }

            if (!last) {
                #pragma unroll
                for (int it = 0; it < 4; ++it) {
                    zs[cur ^ 1][ty + 16 * it][scol] = zf[it];
                    es[cur ^ 1][ty + 16 * it][scol] = ef[it];
                }
            }
            __syncthreads();
            cur ^= 1;
        }

        // chunk epilogue: distances + argmin update
        #pragma unroll
        for (int j = 0; j < 4; ++j) {
            int kk = ch * 64 + tx + 16 * j;
            float e2 = en2[kk];
            #pragma unroll
            for (int i = 0; i < 4; ++i) {
                float dp = (acc[i][j].x + acc[i][j].y) + (acc[i][j].z + acc[i][j].w);
                float val = (z2[i] + e2) - 2.0f * dp;
                if (val < bestV[i]) { bestV[i] = val; bestI[i] = kk; }
            }
        }
    }

    // reduce across the 16 tx lanes; tie -> smaller index
    #pragma unroll
    for (int i = 0; i < 4; ++i) {
        #pragma unroll
        for (int off = 1; off < 16; off <<= 1) {
            float vo = __shfl_xor(bestV[i], off, 16);
            int   io = __shfl_xor(bestI[i], off, 16);
            if (vo < bestV[i] || (vo == bestV[i] && io < bestI[i])) {
                bestV[i] = vo; bestI[i] = io;
            }
        }
        if (tx == 0) {
            int t = t0 + ty + 16 * i;
            idxb[t] = bestI[i];
            idxf[t] = (float)bestI[i];
        }
    }
}

// ---------------- K4: gather epilogue (quant = emb[idx], NCHW) --------------
__global__ void k_gather(const float* __restrict__ emb,
                         const int* __restrict__ idxb, float* __restrict__ out) {
    int o  = blockIdx.x * 256 + threadIdx.x;
    int hw = o & 1023;
    int nc = o >> 10;
    int c  = nc & 255;
    int n  = nc >> 8;
    int t  = (n << 10) | hw;
    int k  = idxb[t];
    out[o] = emb[(size_t)k * CDIM + c];
}

extern "C" void kernel_launch(void* const* d_in, const int* in_sizes, int n_in,
                              void* d_out, int out_size, void* d_ws, size_t ws_size,
                              hipStream_t stream) {
    const float* z   = (const float*)d_in[0];
    const float* emb = (const float*)d_in[1];
    float* out  = (float*)d_out;
    float* znt  = out;                         // quant region doubles as zn scratch
    float* idxf = out + (size_t)NTOK * CDIM;   // index output (float) tail

    float* en   = (float*)d_ws;                // 1 MB
    float* en2  = en + (size_t)KCODE * CDIM;   // 4 KB
    float* znt2 = en2 + KCODE;                 // 128 KB
    int*   idxb = (int*)(znt2 + NTOK);         // 128 KB

    k_norm_emb<<<KCODE, 64, 0, stream>>>(emb, en, en2);
    k_norm_z<<<NTOK / 32, 256, 0, stream>>>(z, znt, znt2);
    k_argmin<<<NTOK / 64, 256, 0, stream>>>(znt, znt2, en, en2, idxb, idxf);
    k_gather<<<(NTOK * CDIM) / 256, 256, 0, stream>>>(emb, idxb, out);
}

// Round 3
// 128.978 us; speedup vs baseline: 7.3587x; 2.8694x over previous
//
#include <hip/hip_runtime.h>

#define NTOK 32768
#define CDIM 256
#define KCODE 1024
#define C4 64   // CDIM/4

typedef __bf16 bf16x8 __attribute__((ext_vector_type(8)));
typedef float  f32x4  __attribute__((ext_vector_type(4)));
typedef const __attribute__((address_space(1))) void* as1cvp;
typedef __attribute__((address_space(3))) void* as3vp;

__device__ __forceinline__ unsigned long long umin64(unsigned long long a, unsigned long long b) { return a < b ? a : b; }
__device__ __forceinline__ unsigned long long umax64(unsigned long long a, unsigned long long b) { return a > b ? a : b; }

// ---------------- K1: normalize codebook -> en fp32, en2, eh/el bf16 --------
__global__ void k_norm_emb(const float* __restrict__ emb,
                           float* __restrict__ en, float* __restrict__ en2,
                           __bf16* __restrict__ eh, __bf16* __restrict__ el) {
    int k = blockIdx.x;
    int l = threadIdx.x;               // 64 lanes, 4 floats each
    float4 v = reinterpret_cast<const float4*>(emb)[k * C4 + l];
    float ss = v.x*v.x + v.y*v.y + v.z*v.z + v.w*v.w;
    #pragma unroll
    for (int o = 32; o >= 1; o >>= 1) ss += __shfl_xor(ss, o, 64);
    float den = fmaxf(sqrtf(ss), 1e-12f);
    float4 e;
    e.x = v.x / den; e.y = v.y / den; e.z = v.z / den; e.w = v.w / den;
    reinterpret_cast<float4*>(en)[k * C4 + l] = e;
    float s2 = e.x*e.x + e.y*e.y + e.z*e.z + e.w*e.w;
    #pragma unroll
    for (int o = 32; o >= 1; o >>= 1) s2 += __shfl_xor(s2, o, 64);
    if (l == 0) en2[k] = s2;

    __bf16* ehp = eh + (size_t)k * CDIM + 4 * l;
    __bf16* elp = el + (size_t)k * CDIM + 4 * l;
    float ev[4] = {e.x, e.y, e.z, e.w};
    #pragma unroll
    for (int q = 0; q < 4; ++q) {
        __bf16 h = (__bf16)ev[q];
        ehp[q] = h;
        elp[q] = (__bf16)(ev[q] - (float)h);
    }
}

// ---------------- K2: transpose+normalize z -> znt fp32, znt2, zh/zl bf16 ---
__global__ void k_norm_z(const float* __restrict__ z,
                         float* __restrict__ znt, float* __restrict__ znt2,
                         __bf16* __restrict__ zh, __bf16* __restrict__ zl) {
    __shared__ float zsb[CDIM * 32];   // 32 KB, [c][ (tok+c)&31 ]
    __shared__ float ssp[256];
    __shared__ float dens[32];
    int tid = threadIdx.x;
    int t0  = blockIdx.x * 32;
    int n   = t0 >> 10;
    int thw0 = t0 & 1023;

    int l = tid & 31, grp = tid >> 5;          // 8 c-stripes
    const float* zb = z + (((size_t)(n * CDIM)) << 10) + thw0 + l;
    float ss = 0.f;
    int c0 = grp * 32;
    for (int cc = 0; cc < 32; ++cc) {
        int c = c0 + cc;
        float v = zb[((size_t)c) << 10];
        zsb[c * 32 + ((l + c) & 31)] = v;
        ss += v * v;
    }
    ssp[tid] = ss;
    __syncthreads();
    if (tid < 32) {
        float tot = 0.f;
        #pragma unroll
        for (int g = 0; g < 8; ++g) tot += ssp[g * 32 + tid];
        dens[tid] = fmaxf(sqrtf(tot), 1e-12f);
    }
    __syncthreads();

    int l2 = tid & 63, tg = tid >> 6;          // 4 token-groups of 8
    for (int it = 0; it < 8; ++it) {
        int tok = tg * 8 + it;
        float den = dens[tok];
        float s2 = 0.f;
        #pragma unroll
        for (int cq = 0; cq < 4; ++cq) {
            int c = cq * 64 + l2;
            float v = zsb[c * 32 + ((tok + c) & 31)] / den;
            size_t off = ((size_t)(t0 + tok)) * CDIM + c;
            znt[off] = v;
            __bf16 h = (__bf16)v;
            zh[off] = h;
            zl[off] = (__bf16)(v - (float)h);
            s2 += v * v;
        }
        #pragma unroll
        for (int o = 32; o >= 1; o >>= 1) s2 += __shfl_xor(s2, o, 64);
        if (l2 == 0) znt2[t0 + tok] = s2;
    }
}

// ---------------- K3: split-bf16 MFMA GEMM + top-2 selection ----------------
// 256 blocks x 512 threads (8 waves: 4M x 2N). BM=128 tokens/block, all 1024
// codes in 16 chunks of 64. A (z hi/lo) hoisted in regs; B (e hi/lo) staged
// in LDS via global_load_lds with pre-swizzled source, double-buffered.
__global__ __launch_bounds__(512, 2) void k_mfma(
        const __bf16* __restrict__ zh, const __bf16* __restrict__ zl,
        const __bf16* __restrict__ eh, const __bf16* __restrict__ el,
        const float* __restrict__ en2, uint2* __restrict__ top2) {
    __shared__ __bf16 ebuf[2][2][64 * 256];    // [buf][h/l], 32KB each = 128KB
    __shared__ unsigned long long t2l[128][2][2];

    int tid = threadIdx.x;
    int l = tid & 63, wid = tid >> 6;
    int mw = wid >> 1, nw = wid & 1;           // 4M x 2N
    int t0 = blockIdx.x * 128;
    int row = l & 15, kg = l >> 4;             // frag row / k-group

    // hoist A: 2 mtiles x 8 ksteps x {hi,lo} = 128 VGPR, z read once
    bf16x8 ah[2][8], al_[2][8];
    #pragma unroll
    for (int mt = 0; mt < 2; ++mt) {
        size_t tok = (size_t)(t0 + mw * 32 + mt * 16 + row);
        const __bf16* ph = zh + tok * CDIM + kg * 8;
        const __bf16* pl = zl + tok * CDIM + kg * 8;
        #pragma unroll
        for (int ks = 0; ks < 8; ++ks) {
            ah[mt][ks]  = *reinterpret_cast<const bf16x8*>(ph + ks * 32);
            al_[mt][ks] = *reinterpret_cast<const bf16x8*>(pl + ks * 32);
        }
    }

    // top-2 keys per lane-token: 2 mtiles x 4 regs
    unsigned long long b1[8], b2[8];
    #pragma unroll
    for (int i = 0; i < 8; ++i) { b1[i] = ~0ull; b2[i] = ~0ull; }

    // stage one 64-code chunk (hi+lo) into ebuf[buf] with XOR swizzle.
    // LDS slot s (16B units) in [64][32] holds logical c16 = (s&31)^(code&15).
    auto stage = [&](int buf, int ch) {
        #pragma unroll
        for (int a = 0; a < 2; ++a) {
            const __bf16* src = a ? el : eh;
            #pragma unroll
            for (int i = 0; i < 4; ++i) {
                int s = i * 512 + tid;
                int code = s >> 5, c16 = s & 31;
                int gslot = c16 ^ (code & 15);
                const __bf16* gp = src + ((size_t)(ch * 64 + code)) * CDIM + gslot * 8;
                __bf16* ld = &ebuf[buf][a][0] + ((size_t)(i * 512 + wid * 64)) * 8;
                __builtin_amdgcn_global_load_lds((as1cvp)gp, (as3vp)ld, 16, 0, 0);
            }
        }
    };

    stage(0, 0);
    __syncthreads();
    int cur = 0;
    for (int ch = 0; ch < 16; ++ch) {
        if (ch < 15) stage(cur ^ 1, ch + 1);

        f32x4 acc[2][2];
        #pragma unroll
        for (int mt = 0; mt < 2; ++mt)
            #pragma unroll
            for (int nt = 0; nt < 2; ++nt)
                #pragma unroll
                for (int r = 0; r < 4; ++r) acc[mt][nt][r] = 0.f;

        #pragma unroll
        for (int ks = 0; ks < 8; ++ks) {
            int c16 = ks * 4 + kg;
            bf16x8 bh[2], bl[2];
            #pragma unroll
            for (int nt = 0; nt < 2; ++nt) {
                int code = nw * 32 + nt * 16 + row;
                int slot = c16 ^ (code & 15);
                bh[nt] = *reinterpret_cast<const bf16x8*>(&ebuf[cur][0][code * 256 + slot * 8]);
                bl[nt] = *reinterpret_cast<const bf16x8*>(&ebuf[cur][1][code * 256 + slot * 8]);
            }
            #pragma unroll
            for (int mt = 0; mt < 2; ++mt)
                #pragma unroll
                for (int nt = 0; nt < 2; ++nt) {
                    acc[mt][nt] = __builtin_amdgcn_mfma_f32_16x16x32_bf16(ah[mt][ks],  bh[nt], acc[mt][nt], 0, 0, 0);
                    acc[mt][nt] = __builtin_amdgcn_mfma_f32_16x16x32_bf16(ah[mt][ks],  bl[nt], acc[mt][nt], 0, 0, 0);
                    acc[mt][nt] = __builtin_amdgcn_mfma_f32_16x16x32_bf16(al_[mt][ks], bh[nt], acc[mt][nt], 0, 0, 0);
                }
        }

        // selection epilogue: d' = e2 - 2*dot (z2 constant per token)
        #pragma unroll
        for (int nt = 0; nt < 2; ++nt) {
            int code = ch * 64 + nw * 32 + nt * 16 + row;
            float e2v = en2[code];
            #pragma unroll
            for (int mt = 0; mt < 2; ++mt)
                #pragma unroll
                for (int r = 0; r < 4; ++r) {
                    float d = e2v - 2.0f * acc[mt][nt][r];
                    unsigned int ub = __float_as_uint(d);
                    ub = (ub & 0x80000000u) ? ~ub : (ub | 0x80000000u);
                    unsigned long long key = ((unsigned long long)ub << 32) | (unsigned)code;
                    int idx = mt * 4 + r;
                    if (key < b1[idx]) { b2[idx] = b1[idx]; b1[idx] = key; }
                    else if (key < b2[idx]) { b2[idx] = key; }
                }
        }
        __syncthreads();
        cur ^= 1;
    }

    // butterfly top-2 merge across the 16 col-lanes
    #pragma unroll
    for (int i = 0; i < 8; ++i) {
        #pragma unroll
        for (int off = 1; off < 16; off <<= 1) {
            unsigned long long o1 = __shfl_xor(b1[i], off, 64);
            unsigned long long o2 = __shfl_xor(b2[i], off, 64);
            unsigned long long m1 = umin64(b1[i], o1);
            unsigned long long m2 = umin64(umax64(b1[i], o1), umin64(b2[i], o2));
            b1[i] = m1; b2[i] = m2;
        }
    }
    if ((l & 15) == 0) {
        #pragma unroll
        for (int mt = 0; mt < 2; ++mt)
            #pragma unroll
            for (int r = 0; r < 4; ++r) {
                int tl = mw * 32 + mt * 16 + kg * 4 + r;   // C/D row mapping
                t2l[tl][nw][0] = b1[mt * 4 + r];
                t2l[tl][nw][1] = b2[mt * 4 + r];
            }
    }
    __syncthreads();
    if (tid < 128) {
        unsigned long long a1 = t2l[tid][0][0], a2 = t2l[tid][0][1];
        unsigned long long c1 = t2l[tid][1][0], c2 = t2l[tid][1][1];
        unsigned long long m1 = umin64(a1, c1);
        unsigned long long m2 = umin64(umax64(a1, c1), umin64(a2, c2));
        top2[t0 + tid] = make_uint2((unsigned)m1, (unsigned)m2);
    }
}

// ---------------- K3b: fp32 fixup of top-2 candidates -----------------------
__global__ void k_fixup(const float* __restrict__ znt, const float* __restrict__ znt2,
                        const float* __restrict__ en,  const float* __restrict__ en2,
                        const uint2* __restrict__ top2,
                        int* __restrict__ idxb, float* __restrict__ idxf) {
    int tid = threadIdx.x;
    int l = tid & 63, wid = tid >> 6;
    int t = blockIdx.x * 4 + wid;
    uint2 cd = top2[t];
    float4 z4 = reinterpret_cast<const float4*>(znt)[(size_t)t * C4 + l];
    float4 ea = reinterpret_cast<const float4*>(en)[(size_t)cd.x * C4 + l];
    float4 eb = reinterpret_cast<const float4*>(en)[(size_t)cd.y * C4 + l];
    float da = z4.x*ea.x + z4.y*ea.y + z4.z*ea.z + z4.w*ea.w;
    float db = z4.x*eb.x + z4.y*eb.y + z4.z*eb.z + z4.w*eb.w;
    #pragma unroll
    for (int o = 32; o >= 1; o >>= 1) {
        da += __shfl_xor(da, o, 64);
        db += __shfl_xor(db, o, 64);
    }
    if (l == 0) {
        float z2 = znt2[t];
        float d1 = (z2 + en2[cd.x]) - 2.0f * da;
        float d2 = (z2 + en2[cd.y]) - 2.0f * db;
        int k = (d2 < d1 || (d2 == d1 && cd.y < cd.x)) ? (int)cd.y : (int)cd.x;
        idxb[t] = k;
        idxf[t] = (float)k;
    }
}

// ---------------- K4: gather epilogue (quant = emb[idx], NCHW) --------------
__global__ void k_gather(const float* __restrict__ emb,
                         const int* __restrict__ idxb, float* __restrict__ out) {
    int o  = blockIdx.x * 256 + threadIdx.x;
    int hw = o & 1023;
    int nc = o >> 10;
    int c  = nc & 255;
    int n  = nc >> 8;
    int t  = (n << 10) | hw;
    int k  = idxb[t];
    out[o] = emb[(size_t)k * CDIM + c];
}

extern "C" void kernel_launch(void* const* d_in, const int* in_sizes, int n_in,
                              void* d_out, int out_size, void* d_ws, size_t ws_size,
                              hipStream_t stream) {
    const float* z   = (const float*)d_in[0];
    const float* emb = (const float*)d_in[1];
    float* out  = (float*)d_out;
    float* znt  = out;                          // quant region doubles as zn scratch
    float* idxf = out + (size_t)NTOK * CDIM;    // index output (float) tail

    float*  en   = (float*)d_ws;                        // 1 MB
    float*  en2  = en + (size_t)KCODE * CDIM;           // 4 KB
    float*  znt2 = en2 + KCODE;                         // 128 KB
    __bf16* eh   = (__bf16*)(znt2 + NTOK);              // 512 KB
    __bf16* el   = eh + (size_t)KCODE * CDIM;           // 512 KB
    __bf16* zh   = el + (size_t)KCODE * CDIM;           // 16 MB
    __bf16* zl   = zh + (size_t)NTOK * CDIM;            // 16 MB
    uint2*  top2 = (uint2*)(zl + (size_t)NTOK * CDIM);  // 256 KB
    int*    idxb = (int*)(top2 + NTOK);                 // 128 KB

    k_norm_emb<<<KCODE, 64, 0, stream>>>(emb, en, en2, eh, el);
    k_norm_z<<<NTOK / 32, 256, 0, stream>>>(z, znt, znt2, zh, zl);
    k_mfma<<<NTOK / 128, 512, 0, stream>>>(zh, zl, eh, el, en2, top2);
    k_fixup<<<NTOK / 4, 256, 0, stream>>>(znt, znt2, en, en2, top2, idxb, idxf);
    k_gather<<<(NTOK * CDIM) / 256, 256, 0, stream>>>(emb, idxb, out);
}